// Round 11
// baseline (2972.019 us; speedup 1.0000x reference)
//
#include <hip/hip_runtime.h>
#include <cstdint>
#include <cstddef>

#define S_LEN 256
#define BATCH 64
#define HID   1024
#define GATES 4096
#define NBLK  256
#define FLAG_STRIDE 32   // 32 uints = 128 B: one cache line per flag

typedef _Float16 h16;
typedef _Float16 h16x8 __attribute__((ext_vector_type(8)));
typedef _Float16 h16x4 __attribute__((ext_vector_type(4)));
typedef float    f32x4 __attribute__((ext_vector_type(4)));

// ---------------------------------------------------------------------------
// x fp32 -> fp16 (one pass)
// ---------------------------------------------------------------------------
__global__ __launch_bounds__(256)
void xconv_kernel(const float* __restrict__ x, h16* __restrict__ x16)
{
  const int n4 = S_LEN * BATCH * HID / 4;
  const int stride = gridDim.x * 256;
  for (int i = blockIdx.x * 256 + threadIdx.x; i < n4; i += stride) {
    f32x4 v = ((const f32x4*)x)[i];
    h16x4 o;
    o[0] = (h16)v[0]; o[1] = (h16)v[1]; o[2] = (h16)v[2]; o[3] = (h16)v[3];
    ((h16x4*)x16)[i] = o;
  }
}

// ---------------------------------------------------------------------------
// Device-scope (sc1) 16B ring load: bypasses L1+L2, reads the L3 coherence
// point directly. Issued WITHOUT an internal wait so 8 of them pipeline;
// one vmcnt(0) + sched_barrier fence before use (rule-18).
// ---------------------------------------------------------------------------
#define RLOAD(dst, ptr, OFFSTR)                                         \
  asm volatile("global_load_dwordx4 %0, %1, off offset:" OFFSTR " sc1"  \
               : "=&v"(dst) : "v"(ptr) : "memory")

// ---------------------------------------------------------------------------
// Flat grid barrier, NO cache maintenance anywhere:
//  - h payload moves via sc1 (write-through stores, device-scope loads), so
//    no acquire/release (buffer_inv / buffer_wbl2) is needed at all.
//  - entry __syncthreads drains vmcnt -> sc1 h-stores are at L3 before the
//    relaxed flag store; consumers' sc1 loads read L3 directly.
// Monotone epochs; flags zeroed per kernel_launch.
// ---------------------------------------------------------------------------
__device__ __forceinline__ void grid_barrier(unsigned* flags, int g, int wg)
{
  __syncthreads();                      // vmcnt drained: sc1 h-stores at L3
  const unsigned tgt = (unsigned)(g + 1);
  if (threadIdx.x == 0)
    __hip_atomic_store(&flags[wg * FLAG_STRIDE], tgt,
                       __ATOMIC_RELAXED, __HIP_MEMORY_SCOPE_AGENT);
  if (threadIdx.x < NBLK) {
    while (__hip_atomic_load(&flags[threadIdx.x * FLAG_STRIDE],
                             __ATOMIC_RELAXED, __HIP_MEMORY_SCOPE_AGENT) < tgt) {}
  }
  __syncthreads();
}

// ---------------------------------------------------------------------------
// Persistent 2-layer pipelined LSTM. 256 WGs x 512 thr (8 waves, 2/SIMD).
// WG wg: layer = wg>>7, owns hidden cols j0..j0+7 (32 gate-cols = 2 n-tiles).
// Wave w owns K-slice [w*256,(w+1)*256): waves 0-3 input part (x or h0),
// waves 4-7 hidden part (h_prev). Weights fp16 in 128KB LDS (loaded once).
// Step g: layer0 does t=g, layer1 does t=g-1.
// Mutable data (h rings): sc1 both directions -> L2 never stale, never dirty.
// Immutable data (x16/weights/bias): plain cached, never invalidated.
// Ring A-frags batch-preloaded to registers (32x16B, one vmcnt wait).
// 8-way cross-wave K-reduce via 16KB XOR-swizzled LDS, 4 m-rounds of 16 rows.
// ---------------------------------------------------------------------------
__global__ __launch_bounds__(512, 1)
void lstm_persistent(const h16* __restrict__ x16,
                     const float* __restrict__ weight,
                     const float* __restrict__ bias,
                     h16* __restrict__ h0r,
                     h16* __restrict__ h1r,
                     unsigned* __restrict__ flags)
{
  __shared__ h16   wlds[65536];        // 128 KB: [8 w][2 n2][8 s][64 lane][8]
  __shared__ float plds[8][16][32];    // 16 KB

  const int wg    = blockIdx.x;
  const int layer = wg >> 7;
  const int j0    = (wg & 127) * 8;
  const int tid   = threadIdx.x;
  const int wave  = tid >> 6, lane = tid & 63;
  const int l15   = lane & 15, l16 = lane >> 4;

  // ---- one-time: pack this WG's weight slice fp32->fp16 into LDS ----
  {
    const float* wsrc = weight + (size_t)layer * 2 * GATES * HID;
    for (int c = tid; c < 8192; c += 512) {   // c = ((w*2+n2)*8+s)*64 + ln
      const int ln = c & 63, s = (c >> 6) & 7, n2 = (c >> 9) & 1, w = c >> 10;
      const int lc  = n2 * 16 + (ln & 15);              // local col 0..31
      const int col = (lc >> 3) * HID + j0 + (lc & 7);  // global gate col
      const int k   = w * 256 + s * 32 + (ln >> 4) * 8; // global K
      const float* p = wsrc + (k < HID ? (size_t)0 : (size_t)GATES * HID)
                            + (size_t)col * HID + (k & (HID - 1));
      h16x8 v;
#pragma unroll
      for (int e = 0; e < 8; ++e) v[e] = (h16)p[e];
      *(h16x8*)&wlds[(size_t)c * 8] = v;
    }
  }
  // combined bias for this thread's j (threads 0-127 use it)
  float bc[4];
  {
    const int j = tid & 7;
#pragma unroll
    for (int gg = 0; gg < 4; ++gg) {
      const int col = gg * HID + j0 + j;
      bc[gg] = bias[(size_t)layer * 2 * GATES + col] +
               bias[(size_t)layer * 2 * GATES + GATES + col];
    }
  }
  float creg[4] = {0.f, 0.f, 0.f, 0.f};
  __syncthreads();

  for (int g = 0; g <= S_LEN; ++g) {
    const bool active = (layer == 0) ? (g < S_LEN) : (g >= 1);
    if (active) {
      const h16 *Alo, *Ahi;
      h16* Hout;
      if (layer == 0) {
        Alo  = x16 + (size_t)g * (BATCH * HID);
        Ahi  = h0r + (size_t)((g + 1) & 1) * (BATCH * HID);
        Hout = h0r + (size_t)(g & 1) * (BATCH * HID);
      } else {
        Alo  = h0r + (size_t)((g - 1) & 1) * (BATCH * HID);
        Ahi  = h1r + (size_t)(g & 1) * (BATCH * HID);
        Hout = h1r + (size_t)((g - 1) & 1) * (BATCH * HID);
      }
      const h16* Asrc = (wave < 4) ? Alo : Ahi;
      const bool ring = (layer == 1) || (wave >= 4);   // wave-uniform
      const int kb = (wave & 3) * 256;

      const h16* arow[4];
#pragma unroll
      for (int i = 0; i < 4; ++i)
        arow[i] = Asrc + (size_t)(i * 16 + l15) * HID + kb + l16 * 8;
      const h16* bb = wlds + (size_t)wave * 8192 + lane * 8;  // n2 stride 4096

      // ---- A-frag preload: [s][i], 32 x 16B ----
      h16x8 a[8][4];
      if (ring) {
#pragma unroll
        for (int i = 0; i < 4; ++i) {
          RLOAD(a[0][i], arow[i], "0");
          RLOAD(a[1][i], arow[i], "64");
          RLOAD(a[2][i], arow[i], "128");
          RLOAD(a[3][i], arow[i], "192");
          RLOAD(a[4][i], arow[i], "256");
          RLOAD(a[5][i], arow[i], "320");
          RLOAD(a[6][i], arow[i], "384");
          RLOAD(a[7][i], arow[i], "448");
        }
        asm volatile("s_waitcnt vmcnt(0)" ::: "memory");
        __builtin_amdgcn_sched_barrier(0);
      } else {
#pragma unroll
        for (int s = 0; s < 8; ++s)
#pragma unroll
          for (int i = 0; i < 4; ++i)
            a[s][i] = *(const h16x8*)(arow[i] + s * 32);
      }

      f32x4 acc[4][2];
#pragma unroll
      for (int i = 0; i < 4; ++i)
#pragma unroll
        for (int n2 = 0; n2 < 2; ++n2) acc[i][n2] = (f32x4)0.f;

#pragma unroll
      for (int s = 0; s < 8; ++s) {
        const h16x8 b0 = *(const h16x8*)(bb + s * 512);
        const h16x8 b1 = *(const h16x8*)(bb + 4096 + s * 512);
#pragma unroll
        for (int i = 0; i < 4; ++i) {
          acc[i][0] = __builtin_amdgcn_mfma_f32_16x16x32_f16(a[s][i], b0, acc[i][0], 0, 0, 0);
          acc[i][1] = __builtin_amdgcn_mfma_f32_16x16x32_f16(a[s][i], b1, acc[i][1], 0, 0, 0);
        }
      }

      // ---- 8-way cross-wave reduce + activations, 4 m-rounds of 16 rows ----
#pragma unroll
      for (int i = 0; i < 4; ++i) {
#pragma unroll
        for (int n2 = 0; n2 < 2; ++n2)
#pragma unroll
          for (int q = 0; q < 4; ++q) {
            const int r = l16 * 4 + q;                        // 0..15
            const int colS = (n2 * 16 + l15) ^ ((r & 7) << 2);
            plds[wave][r][colS] = acc[i][n2][q];
          }
        __syncthreads();
        if (tid < 128) {
          const int r = tid >> 3, j = tid & 7;
          float gv[4];
#pragma unroll
          for (int gg = 0; gg < 4; ++gg) {
            const int colS = (gg * 8 + j) ^ ((r & 7) << 2);
            float s = bc[gg];
#pragma unroll
            for (int w = 0; w < 8; ++w) s += plds[w][r][colS];
            gv[gg] = s;
          }
          const float ig = 1.f / (1.f + __expf(-gv[0]));
          const float fg = 1.f / (1.f + __expf(-gv[1]));
          const float gt = 1.f - 2.f / (__expf(2.f * gv[2]) + 1.f);
          const float og = 1.f / (1.f + __expf(-gv[3]));
          const float cn = fg * creg[i] + ig * gt;
          creg[i] = cn;
          const float th = 1.f - 2.f / (__expf(2.f * cn) + 1.f);
          union { h16 f; unsigned short u; } hb;
          hb.f = (h16)(og * th);
          __hip_atomic_store(
              (unsigned short*)&Hout[(size_t)(i * 16 + r) * HID + j0 + j],
              hb.u, __ATOMIC_RELAXED, __HIP_MEMORY_SCOPE_AGENT);
        }
        __syncthreads();
      }
    }
    grid_barrier(flags, g, wg);
  }
}

// ---------------------------------------------------------------------------
// out[m][cls] = h[m] . fc_w[cls] + fc_b[cls]. One wave per output.
// ---------------------------------------------------------------------------
__global__ __launch_bounds__(256)
void fc_kernel(const h16* __restrict__ h,
               const float* __restrict__ fw,
               const float* __restrict__ fb,
               float* __restrict__ out)
{
  const int gw = (blockIdx.x * blockDim.x + threadIdx.x) >> 6;
  const int lane = threadIdx.x & 63;
  if (gw >= BATCH * 10) return;
  const int m = gw / 10, cls = gw % 10;
  float s = 0.f;
  for (int k = lane; k < HID; k += 64)
    s += (float)h[(size_t)m * HID + k] * fw[(size_t)cls * HID + k];
#pragma unroll
  for (int off = 32; off; off >>= 1) s += __shfl_down(s, off);
  if (lane == 0) out[m * 10 + cls] = s + fb[cls];
}

// ---------------------------------------------------------------------------
extern "C" void kernel_launch(void* const* d_in, const int* in_sizes, int n_in,
                              void* d_out, int out_size, void* d_ws, size_t ws_size,
                              hipStream_t stream)
{
  const float* x      = (const float*)d_in[0];   // [256][64][1024]
  const float* weight = (const float*)d_in[1];   // [2][2][4096][1024]
  const float* bias   = (const float*)d_in[2];   // [2][2][4096]
  const float* fc_w   = (const float*)d_in[3];   // [10][1024]
  const float* fc_b   = (const float*)d_in[4];   // [10]
  float* out = (float*)d_out;                    // [64][10]

  auto align = [](size_t v) { return (v + 255) & ~(size_t)255; };
  const size_t flags_sz = (size_t)NBLK * FLAG_STRIDE * sizeof(unsigned); // 32 KB
  const size_t x16_sz  = (size_t)S_LEN * BATCH * HID * sizeof(h16);      // 32 MB
  const size_t ring_sz = (size_t)2 * BATCH * HID * sizeof(h16);          // 256 KB

  char* p = (char*)d_ws;
  unsigned* flags = (unsigned*)p; p += align(flags_sz);
  h16* x16 = (h16*)p; p += align(x16_sz);
  h16* h0r = (h16*)p; p += align(ring_sz);
  h16* h1r = (h16*)p; p += align(ring_sz);

  hipMemsetAsync(flags, 0, flags_sz, stream);
  hipMemsetAsync(h0r, 0, ring_sz, stream);
  hipMemsetAsync(h1r, 0, ring_sz, stream);

  xconv_kernel<<<dim3(2048), 256, 0, stream>>>(x, x16);

  lstm_persistent<<<dim3(NBLK), dim3(512), 0, stream>>>(
      x16, weight, bias, h0r, h1r, flags);

  // final h of top layer: t = 255 -> ring slot 1
  fc_kernel<<<dim3((BATCH * 10 * 64) / 256), 256, 0, stream>>>(
      h1r + (size_t)BATCH * HID, fc_w, fc_b, out);
}

// Round 12
// 2899.614 us; speedup vs baseline: 1.0250x; 1.0250x over previous
//
#include <hip/hip_runtime.h>
#include <cstdint>
#include <cstddef>

#define S_LEN 256
#define BATCH 64
#define HID   1024
#define GATES 4096
#define NBLK  256
#define RING_D 4         // h0 ring depth (layer-0 may run ahead by D-1 steps)
#define FLAG_STRIDE 32   // 32 uints = 128 B: one cache line per flag

typedef _Float16 h16;
typedef _Float16 h16x8 __attribute__((ext_vector_type(8)));
typedef _Float16 h16x4 __attribute__((ext_vector_type(4)));
typedef float    f32x4 __attribute__((ext_vector_type(4)));

// ---------------------------------------------------------------------------
// x fp32 -> fp16 (one pass)
// ---------------------------------------------------------------------------
__global__ __launch_bounds__(256)
void xconv_kernel(const float* __restrict__ x, h16* __restrict__ x16)
{
  const int n4 = S_LEN * BATCH * HID / 4;
  const int stride = gridDim.x * 256;
  for (int i = blockIdx.x * 256 + threadIdx.x; i < n4; i += stride) {
    f32x4 v = ((const f32x4*)x)[i];
    h16x4 o;
    o[0] = (h16)v[0]; o[1] = (h16)v[1]; o[2] = (h16)v[2]; o[3] = (h16)v[3];
    ((h16x4*)x16)[i] = o;
  }
}

// ---------------------------------------------------------------------------
// Device-scope (sc1) 16B ring load: bypasses L1+L2, reads the L3 coherence
// point directly. Issued WITHOUT an internal wait so they pipeline; one
// vmcnt(0) + sched_barrier fence before use (rule-18).
// ---------------------------------------------------------------------------
#define RLOAD(dst, ptr, OFFSTR)                                         \
  asm volatile("global_load_dwordx4 %0, %1, off offset:" OFFSTR " sc1"  \
               : "=&v"(dst) : "v"(ptr) : "memory")

// ---------------------------------------------------------------------------
// Persistent 2-layer DECOUPLED-pipeline LSTM. 256 WGs x 512 thr.
// Group 0 = blocks 0..127 (layer 0), group 1 = blocks 128..255 (layer 1).
// Each group runs its own t = 0..255 loop with an intra-group barrier;
// cross-group dependencies are slack waits:
//   layer0 @ t: own group >= t, layer1 >= t+1-RING_D (h0-slot overwrite safe)
//   layer1 @ t: own group >= t, layer0 >= t+1      (h0[t] fully written)
// h0 ring depth RING_D (slot t%D), h1 ring depth 2. All mutable data (h
// rings) moves sc1 (write-through stores / device-scope loads) -> no
// acquire/release cache maintenance anywhere. x16/weights/bias: plain cached.
// Per block: 32 gate-cols, 8 waves K-split (waves 0-3 input part, 4-7 hidden
// part), weights fp16 in 128KB LDS, 8-way K-reduce in 16KB swizzled LDS.
// ---------------------------------------------------------------------------
__global__ __launch_bounds__(512, 1)
void lstm_persistent(const h16* __restrict__ x16,
                     const float* __restrict__ weight,
                     const float* __restrict__ bias,
                     h16* __restrict__ h0r,
                     h16* __restrict__ h1r,
                     unsigned* __restrict__ flags)
{
  __shared__ h16   wlds[65536];        // 128 KB: [8 w][2 n2][8 s][64 lane][8]
  __shared__ float plds[8][16][32];    // 16 KB

  const int wg    = blockIdx.x;
  const int layer = wg >> 7;
  const int j0    = (wg & 127) * 8;
  const int tid   = threadIdx.x;
  const int wave  = tid >> 6, lane = tid & 63;
  const int l15   = lane & 15, l16 = lane >> 4;
  const int BH    = BATCH * HID;

  // ---- one-time: pack this WG's weight slice fp32->fp16 into LDS ----
  {
    const float* wsrc = weight + (size_t)layer * 2 * GATES * HID;
    for (int c = tid; c < 8192; c += 512) {   // c = ((w*2+n2)*8+s)*64 + ln
      const int ln = c & 63, s = (c >> 6) & 7, n2 = (c >> 9) & 1, w = c >> 10;
      const int lc  = n2 * 16 + (ln & 15);              // local col 0..31
      const int col = (lc >> 3) * HID + j0 + (lc & 7);  // global gate col
      const int k   = w * 256 + s * 32 + (ln >> 4) * 8; // global K
      const float* p = wsrc + (k < HID ? (size_t)0 : (size_t)GATES * HID)
                            + (size_t)col * HID + (k & (HID - 1));
      h16x8 v;
#pragma unroll
      for (int e = 0; e < 8; ++e) v[e] = (h16)p[e];
      *(h16x8*)&wlds[(size_t)c * 8] = v;
    }
  }
  // combined bias for this thread's j (threads 0-127 use it)
  float bc[4];
  {
    const int j = tid & 7;
#pragma unroll
    for (int gg = 0; gg < 4; ++gg) {
      const int col = gg * HID + j0 + j;
      bc[gg] = bias[(size_t)layer * 2 * GATES + col] +
               bias[(size_t)layer * 2 * GATES + GATES + col];
    }
  }
  float creg[4] = {0.f, 0.f, 0.f, 0.f};
  __syncthreads();

  const int own_base = layer * 128;
  const int oth_base = (1 - layer) * 128;

  for (int t = 0; t < S_LEN; ++t) {
    // ---- start-of-step wait: own group @ t-1 done; cross-group slack ----
    {
      if (tid < 128) {
        const unsigned tg = (unsigned)t;
        if (tg)
          while (__hip_atomic_load(&flags[(own_base + tid) * FLAG_STRIDE],
                                   __ATOMIC_RELAXED,
                                   __HIP_MEMORY_SCOPE_AGENT) < tg) {}
      } else if (tid < 256) {
        const int ct = layer ? (t + 1) : (t + 1 - RING_D);
        if (ct > 0) {
          const unsigned tg = (unsigned)ct;
          while (__hip_atomic_load(&flags[(oth_base + tid - 128) * FLAG_STRIDE],
                                   __ATOMIC_RELAXED,
                                   __HIP_MEMORY_SCOPE_AGENT) < tg) {}
        }
      }
      __syncthreads();
    }

    // ---- pointers for this step ----
    const h16 *Alo, *Ahi;
    h16* Hout;
    if (layer == 0) {
      Alo  = x16 + (size_t)t * BH;                         // plain cached
      Ahi  = h0r + (size_t)((t + RING_D - 1) % RING_D) * BH;  // h0[t-1]
      Hout = h0r + (size_t)(t % RING_D) * BH;                 // h0[t]
    } else {
      Alo  = h0r + (size_t)(t % RING_D) * BH;                 // h0[t]
      Ahi  = h1r + (size_t)((t + 1) & 1) * BH;                // h1[t-1]
      Hout = h1r + (size_t)(t & 1) * BH;                      // h1[t]
    }
    const h16* Asrc = (wave < 4) ? Alo : Ahi;
    const bool ring = (layer == 1) || (wave >= 4);   // wave-uniform
    const int kb = (wave & 3) * 256;

    const h16* arow[4];
#pragma unroll
    for (int i = 0; i < 4; ++i)
      arow[i] = Asrc + (size_t)(i * 16 + l15) * HID + kb + l16 * 8;
    const h16* bb = wlds + (size_t)wave * 8192 + lane * 8;  // n2 stride 4096

    // ---- A-frag preload: [s][i], 32 x 16B ----
    h16x8 a[8][4];
    if (ring) {
#pragma unroll
      for (int i = 0; i < 4; ++i) {
        RLOAD(a[0][i], arow[i], "0");
        RLOAD(a[1][i], arow[i], "64");
        RLOAD(a[2][i], arow[i], "128");
        RLOAD(a[3][i], arow[i], "192");
        RLOAD(a[4][i], arow[i], "256");
        RLOAD(a[5][i], arow[i], "320");
        RLOAD(a[6][i], arow[i], "384");
        RLOAD(a[7][i], arow[i], "448");
      }
      asm volatile("s_waitcnt vmcnt(0)" ::: "memory");
      __builtin_amdgcn_sched_barrier(0);
    } else {
#pragma unroll
      for (int s = 0; s < 8; ++s)
#pragma unroll
        for (int i = 0; i < 4; ++i)
          a[s][i] = *(const h16x8*)(arow[i] + s * 32);
    }

    f32x4 acc[4][2];
#pragma unroll
    for (int i = 0; i < 4; ++i)
#pragma unroll
      for (int n2 = 0; n2 < 2; ++n2) acc[i][n2] = (f32x4)0.f;

#pragma unroll
    for (int s = 0; s < 8; ++s) {
      const h16x8 b0 = *(const h16x8*)(bb + s * 512);
      const h16x8 b1 = *(const h16x8*)(bb + 4096 + s * 512);
#pragma unroll
      for (int i = 0; i < 4; ++i) {
        acc[i][0] = __builtin_amdgcn_mfma_f32_16x16x32_f16(a[s][i], b0, acc[i][0], 0, 0, 0);
        acc[i][1] = __builtin_amdgcn_mfma_f32_16x16x32_f16(a[s][i], b1, acc[i][1], 0, 0, 0);
      }
    }

    // ---- 8-way cross-wave reduce + activations, 4 m-rounds of 16 rows ----
#pragma unroll
    for (int i = 0; i < 4; ++i) {
#pragma unroll
      for (int n2 = 0; n2 < 2; ++n2)
#pragma unroll
        for (int q = 0; q < 4; ++q) {
          const int r = l16 * 4 + q;                        // 0..15
          const int colS = (n2 * 16 + l15) ^ ((r & 7) << 2);
          plds[wave][r][colS] = acc[i][n2][q];
        }
      __syncthreads();
      if (tid < 128) {
        const int r = tid >> 3, j = tid & 7;
        float gv[4];
#pragma unroll
        for (int gg = 0; gg < 4; ++gg) {
          const int colS = (gg * 8 + j) ^ ((r & 7) << 2);
          float s = bc[gg];
#pragma unroll
          for (int w = 0; w < 8; ++w) s += plds[w][r][colS];
          gv[gg] = s;
        }
        const float ig = 1.f / (1.f + __expf(-gv[0]));
        const float fg = 1.f / (1.f + __expf(-gv[1]));
        const float gt = 1.f - 2.f / (__expf(2.f * gv[2]) + 1.f);
        const float og = 1.f / (1.f + __expf(-gv[3]));
        const float cn = fg * creg[i] + ig * gt;
        creg[i] = cn;
        const float th = 1.f - 2.f / (__expf(2.f * cn) + 1.f);
        union { h16 f; unsigned short u; } hb;
        hb.f = (h16)(og * th);
        __hip_atomic_store(
            (unsigned short*)&Hout[(size_t)(i * 16 + r) * HID + j0 + j],
            hb.u, __ATOMIC_RELAXED, __HIP_MEMORY_SCOPE_AGENT);
      }
      __syncthreads();   // also drains vmcnt: h-stores at L3 before flag
    }

    // ---- publish step completion (h stores drained by last syncthreads) ----
    if (tid == 0)
      __hip_atomic_store(&flags[wg * FLAG_STRIDE], (unsigned)(t + 1),
                         __ATOMIC_RELAXED, __HIP_MEMORY_SCOPE_AGENT);
  }
}

// ---------------------------------------------------------------------------
// out[m][cls] = h[m] . fc_w[cls] + fc_b[cls]. One wave per output.
// ---------------------------------------------------------------------------
__global__ __launch_bounds__(256)
void fc_kernel(const h16* __restrict__ h,
               const float* __restrict__ fw,
               const float* __restrict__ fb,
               float* __restrict__ out)
{
  const int gw = (blockIdx.x * blockDim.x + threadIdx.x) >> 6;
  const int lane = threadIdx.x & 63;
  if (gw >= BATCH * 10) return;
  const int m = gw / 10, cls = gw % 10;
  float s = 0.f;
  for (int k = lane; k < HID; k += 64)
    s += (float)h[(size_t)m * HID + k] * fw[(size_t)cls * HID + k];
#pragma unroll
  for (int off = 32; off; off >>= 1) s += __shfl_down(s, off);
  if (lane == 0) out[m * 10 + cls] = s + fb[cls];
}

// ---------------------------------------------------------------------------
extern "C" void kernel_launch(void* const* d_in, const int* in_sizes, int n_in,
                              void* d_out, int out_size, void* d_ws, size_t ws_size,
                              hipStream_t stream)
{
  const float* x      = (const float*)d_in[0];   // [256][64][1024]
  const float* weight = (const float*)d_in[1];   // [2][2][4096][1024]
  const float* bias   = (const float*)d_in[2];   // [2][2][4096]
  const float* fc_w   = (const float*)d_in[3];   // [10][1024]
  const float* fc_b   = (const float*)d_in[4];   // [10]
  float* out = (float*)d_out;                    // [64][10]

  auto align = [](size_t v) { return (v + 255) & ~(size_t)255; };
  const size_t flags_sz = (size_t)NBLK * FLAG_STRIDE * sizeof(unsigned);   // 32 KB
  const size_t x16_sz   = (size_t)S_LEN * BATCH * HID * sizeof(h16);       // 32 MB
  const size_t h0r_sz   = (size_t)RING_D * BATCH * HID * sizeof(h16);      // 512 KB
  const size_t h1r_sz   = (size_t)2 * BATCH * HID * sizeof(h16);           // 256 KB

  char* p = (char*)d_ws;
  unsigned* flags = (unsigned*)p; p += align(flags_sz);
  h16* x16 = (h16*)p; p += align(x16_sz);
  h16* h0r = (h16*)p; p += align(h0r_sz);
  h16* h1r = (h16*)p; p += align(h1r_sz);

  hipMemsetAsync(flags, 0, flags_sz, stream);
  hipMemsetAsync(h0r, 0, h0r_sz, stream);
  hipMemsetAsync(h1r, 0, h1r_sz, stream);

  xconv_kernel<<<dim3(2048), 256, 0, stream>>>(x, x16);

  lstm_persistent<<<dim3(NBLK), dim3(512), 0, stream>>>(
      x16, weight, bias, h0r, h1r, flags);

  // final h of top layer: t = 255 -> h1 ring slot 1
  fc_kernel<<<dim3((BATCH * 10 * 64) / 256), 256, 0, stream>>>(
      h1r + (size_t)BATCH * HID, fc_w, fc_b, out);
}

// Round 13
// 2701.779 us; speedup vs baseline: 1.1000x; 1.0732x over previous
//
#include <hip/hip_runtime.h>
#include <cstdint>
#include <cstddef>

#define S_LEN 256
#define BATCH 64
#define HID   1024
#define GATES 4096
#define NBLK  256
#define RING_D 4         // h0 ring depth
#define FLAG_STRIDE 32   // 32 uints = 128 B: one cache line per flag

typedef _Float16 h16;
typedef _Float16 h16x8 __attribute__((ext_vector_type(8)));
typedef _Float16 h16x4 __attribute__((ext_vector_type(4)));
typedef float    f32x4 __attribute__((ext_vector_type(4)));

// ---------------------------------------------------------------------------
// x fp32 -> fp16 (one pass)
// ---------------------------------------------------------------------------
__global__ __launch_bounds__(256)
void xconv_kernel(const float* __restrict__ x, h16* __restrict__ x16)
{
  const int n4 = S_LEN * BATCH * HID / 4;
  const int stride = gridDim.x * 256;
  for (int i = blockIdx.x * 256 + threadIdx.x; i < n4; i += stride) {
    f32x4 v = ((const f32x4*)x)[i];
    h16x4 o;
    o[0] = (h16)v[0]; o[1] = (h16)v[1]; o[2] = (h16)v[2]; o[3] = (h16)v[3];
    ((h16x4*)x16)[i] = o;
  }
}

// ---------------------------------------------------------------------------
// Device-scope (sc1) 16B load: bypasses L1+L2, reads L3 coherence point.
// Issued without internal wait so batches pipeline; caller fences with
// vmcnt(0) + sched_barrier(0) before use (rule-18).
// ---------------------------------------------------------------------------
#define RLOAD(dst, ptr, OFFSTR)                                         \
  asm volatile("global_load_dwordx4 %0, %1, off offset:" OFFSTR " sc1"  \
               : "=&v"(dst) : "v"(ptr) : "memory")

// ---------------------------------------------------------------------------
// Persistent 2-layer decoupled-pipeline LSTM with SHADOWED INPUT GEMM.
// 256 WGs x 512 thr (8 waves). Group 0 = blocks 0..127 (layer 0), group 1 =
// blocks 128..255 (layer 1). Per block: 32 gate-cols (j0..j0+7 per gate).
//
// Each iteration t:
//   SHADOW : accI = input-half partials (K=1024: x16[t] for L0 / h0[t] for L1,
//            L1 first slack-waits L0 flags >= t+1). Off the critical chain.
//   WAIT   : own group flags >= t (h_own[t-1] ready); L0 also waits
//            L1 >= t+1-RING_D (h0 slot overwrite safety).
//   CRITICAL: load h_own[t-1] (K=1024 8-way split, 16x16B sc1 loads),
//            32 MFMAs on top of accI, 8-way LDS reduce + activations,
//            sc1 write-through h stores, publish flag t+1.
//
// Weights fp16 in 128KB LDS: [part][wave][n2][s][lane][8], part 0 = W_ih,
// part 1 = W_hh, per-wave K-slice 128 per part.
// No cache maintenance anywhere (R11-proven): mutable data all-sc1,
// immutable (x16/weights/bias) plain cached.
// ---------------------------------------------------------------------------
__global__ __launch_bounds__(512, 1)
void lstm_persistent(const h16* __restrict__ x16,
                     const float* __restrict__ weight,
                     const float* __restrict__ bias,
                     h16* __restrict__ h0r,
                     h16* __restrict__ h1r,
                     unsigned* __restrict__ flags)
{
  __shared__ h16   wlds[65536];        // 128 KB
  __shared__ float plds[8][16][32];    // 16 KB

  const int wg    = blockIdx.x;
  const int layer = wg >> 7;
  const int j0    = (wg & 127) * 8;
  const int tid   = threadIdx.x;
  const int wave  = tid >> 6, lane = tid & 63;
  const int l15   = lane & 15, l16 = lane >> 4;
  const int BH    = BATCH * HID;

  // ---- one-time: pack weights fp32->fp16 into LDS ----
  // c = (((part*8 + w)*2 + n2)*4 + s)*64 + ln
  {
    const float* wsrc = weight + (size_t)layer * 2 * GATES * HID;
    for (int c = tid; c < 8192; c += 512) {
      const int ln = c & 63, s = (c >> 6) & 3, n2 = (c >> 8) & 1,
                w = (c >> 9) & 7, part = c >> 12;
      const int lc  = n2 * 16 + (ln & 15);              // local col 0..31
      const int col = (lc >> 3) * HID + j0 + (lc & 7);  // global gate col
      const int k   = w * 128 + s * 32 + (ln >> 4) * 8; // K within part
      const float* p = wsrc + (part ? (size_t)GATES * HID : (size_t)0)
                            + (size_t)col * HID + k;
      h16x8 v;
#pragma unroll
      for (int e = 0; e < 8; ++e) v[e] = (h16)p[e];
      *(h16x8*)&wlds[(size_t)c * 8] = v;
    }
  }
  // combined bias (threads 0-127 use it)
  float bc[4];
  {
    const int j = tid & 7;
#pragma unroll
    for (int gg = 0; gg < 4; ++gg) {
      const int col = gg * HID + j0 + j;
      bc[gg] = bias[(size_t)layer * 2 * GATES + col] +
               bias[(size_t)layer * 2 * GATES + GATES + col];
    }
  }
  float creg[4] = {0.f, 0.f, 0.f, 0.f};
  __syncthreads();

  const int own_base = layer * 128;
  const int oth_base = (1 - layer) * 128;
  const h16* bbI = wlds + (size_t)wave * 4096 + lane * 8;  // input-part B
  const h16* bbH = bbI + 32768;                            // hidden-part B
  const int kw = wave * 128 + l16 * 8;                     // per-wave K base

  for (int t = 0; t < S_LEN; ++t) {
    // ================= SHADOW: input-half partials for step t ==============
    const h16* As;
    if (layer == 0) {
      As = x16 + (size_t)t * BH;                       // always ready
    } else {
      if (tid >= 128 && tid < 256) {                   // slack wait: L0 >= t+1
        const unsigned tg = (unsigned)(t + 1);
        while (__hip_atomic_load(&flags[(oth_base + tid - 128) * FLAG_STRIDE],
                                 __ATOMIC_RELAXED,
                                 __HIP_MEMORY_SCOPE_AGENT) < tg) {}
      }
      __syncthreads();
      As = h0r + (size_t)(t % RING_D) * BH;
    }

    f32x4 accI[4][2];
#pragma unroll
    for (int i = 0; i < 4; ++i)
#pragma unroll
      for (int n2 = 0; n2 < 2; ++n2) accI[i][n2] = (f32x4)0.f;

#pragma unroll
    for (int sc = 0; sc < 2; ++sc) {
      h16x8 aS[2][4];
      if (layer == 0) {
#pragma unroll
        for (int ss = 0; ss < 2; ++ss)
#pragma unroll
          for (int i = 0; i < 4; ++i)
            aS[ss][i] = *(const h16x8*)(As + (size_t)(i * 16 + l15) * HID +
                                        kw + (sc * 2 + ss) * 32);
      } else {
#pragma unroll
        for (int i = 0; i < 4; ++i) {
          const h16* ap = As + (size_t)(i * 16 + l15) * HID + kw + sc * 64;
          RLOAD(aS[0][i], ap, "0");
          RLOAD(aS[1][i], ap, "64");
        }
        asm volatile("s_waitcnt vmcnt(0)" ::: "memory");
        __builtin_amdgcn_sched_barrier(0);
      }
#pragma unroll
      for (int ss = 0; ss < 2; ++ss) {
        const int s = sc * 2 + ss;
        const h16x8 b0 = *(const h16x8*)(bbI + s * 512);
        const h16x8 b1 = *(const h16x8*)(bbI + 2048 + s * 512);
#pragma unroll
        for (int i = 0; i < 4; ++i) {
          accI[i][0] = __builtin_amdgcn_mfma_f32_16x16x32_f16(aS[ss][i], b0, accI[i][0], 0, 0, 0);
          accI[i][1] = __builtin_amdgcn_mfma_f32_16x16x32_f16(aS[ss][i], b1, accI[i][1], 0, 0, 0);
        }
      }
    }

    // ================= WAIT: own group @ t; L0 slot-safety ================
    if (tid < 128) {
      if (t) {
        const unsigned tg = (unsigned)t;
        while (__hip_atomic_load(&flags[(own_base + tid) * FLAG_STRIDE],
                                 __ATOMIC_RELAXED,
                                 __HIP_MEMORY_SCOPE_AGENT) < tg) {}
      }
    } else if (tid < 256 && layer == 0) {
      const int ct = t + 1 - RING_D;
      if (ct > 0) {
        const unsigned tg = (unsigned)ct;
        while (__hip_atomic_load(&flags[(oth_base + tid - 128) * FLAG_STRIDE],
                                 __ATOMIC_RELAXED,
                                 __HIP_MEMORY_SCOPE_AGENT) < tg) {}
      }
    }
    __syncthreads();

    // ================= CRITICAL: hidden-half + reduce + publish ===========
    const h16* Ah;                    // h_own[t-1]
    h16* Hout;                        // h_own[t]
    if (layer == 0) {
      Ah   = h0r + (size_t)((t + RING_D - 1) % RING_D) * BH;
      Hout = h0r + (size_t)(t % RING_D) * BH;
    } else {
      Ah   = h1r + (size_t)((t + 1) & 1) * BH;
      Hout = h1r + (size_t)(t & 1) * BH;
    }

    h16x8 aH[4][4];
#pragma unroll
    for (int i = 0; i < 4; ++i) {
      const h16* ap = Ah + (size_t)(i * 16 + l15) * HID + kw;
      RLOAD(aH[i][0], ap, "0");
      RLOAD(aH[i][1], ap, "64");
      RLOAD(aH[i][2], ap, "128");
      RLOAD(aH[i][3], ap, "192");
    }
    asm volatile("s_waitcnt vmcnt(0)" ::: "memory");
    __builtin_amdgcn_sched_barrier(0);

    f32x4 acc[4][2];
#pragma unroll
    for (int i = 0; i < 4; ++i)
#pragma unroll
      for (int n2 = 0; n2 < 2; ++n2) acc[i][n2] = accI[i][n2];

#pragma unroll
    for (int s = 0; s < 4; ++s) {
      const h16x8 b0 = *(const h16x8*)(bbH + s * 512);
      const h16x8 b1 = *(const h16x8*)(bbH + 2048 + s * 512);
#pragma unroll
      for (int i = 0; i < 4; ++i) {
        acc[i][0] = __builtin_amdgcn_mfma_f32_16x16x32_f16(aH[i][s], b0, acc[i][0], 0, 0, 0);
        acc[i][1] = __builtin_amdgcn_mfma_f32_16x16x32_f16(aH[i][s], b1, acc[i][1], 0, 0, 0);
      }
    }

    // ---- 8-way cross-wave reduce + activations, 4 m-rounds of 16 rows ----
#pragma unroll
    for (int i = 0; i < 4; ++i) {
#pragma unroll
      for (int n2 = 0; n2 < 2; ++n2)
#pragma unroll
        for (int q = 0; q < 4; ++q) {
          const int r = l16 * 4 + q;                        // 0..15
          const int colS = (n2 * 16 + l15) ^ ((r & 7) << 2);
          plds[wave][r][colS] = acc[i][n2][q];
        }
      __syncthreads();
      if (tid < 128) {
        const int r = tid >> 3, j = tid & 7;
        float gv[4];
#pragma unroll
        for (int gg = 0; gg < 4; ++gg) {
          const int colS = (gg * 8 + j) ^ ((r & 7) << 2);
          float s = bc[gg];
#pragma unroll
          for (int w = 0; w < 8; ++w) s += plds[w][r][colS];
          gv[gg] = s;
        }
        const float ig = 1.f / (1.f + __expf(-gv[0]));
        const float fg = 1.f / (1.f + __expf(-gv[1]));
        const float gt = 1.f - 2.f / (__expf(2.f * gv[2]) + 1.f);
        const float og = 1.f / (1.f + __expf(-gv[3]));
        const float cn = fg * creg[i] + ig * gt;
        creg[i] = cn;
        const float th = 1.f - 2.f / (__expf(2.f * cn) + 1.f);
        union { h16 f; unsigned short u; } hb;
        hb.f = (h16)(og * th);
        __hip_atomic_store(
            (unsigned short*)&Hout[(size_t)(i * 16 + r) * HID + j0 + j],
            hb.u, __ATOMIC_RELAXED, __HIP_MEMORY_SCOPE_AGENT);
      }
      __syncthreads();   // drains vmcnt: h-stores at L3 before flag
    }

    // ---- publish step completion ----
    if (tid == 0)
      __hip_atomic_store(&flags[wg * FLAG_STRIDE], (unsigned)(t + 1),
                         __ATOMIC_RELAXED, __HIP_MEMORY_SCOPE_AGENT);
  }
}

// ---------------------------------------------------------------------------
// out[m][cls] = h[m] . fc_w[cls] + fc_b[cls]. One wave per output.
// ---------------------------------------------------------------------------
__global__ __launch_bounds__(256)
void fc_kernel(const h16* __restrict__ h,
               const float* __restrict__ fw,
               const float* __restrict__ fb,
               float* __restrict__ out)
{
  const int gw = (blockIdx.x * blockDim.x + threadIdx.x) >> 6;
  const int lane = threadIdx.x & 63;
  if (gw >= BATCH * 10) return;
  const int m = gw / 10, cls = gw % 10;
  float s = 0.f;
  for (int k = lane; k < HID; k += 64)
    s += (float)h[(size_t)m * HID + k] * fw[(size_t)cls * HID + k];
#pragma unroll
  for (int off = 32; off; off >>= 1) s += __shfl_down(s, off);
  if (lane == 0) out[m * 10 + cls] = s + fb[cls];
}

// ---------------------------------------------------------------------------
extern "C" void kernel_launch(void* const* d_in, const int* in_sizes, int n_in,
                              void* d_out, int out_size, void* d_ws, size_t ws_size,
                              hipStream_t stream)
{
  const float* x      = (const float*)d_in[0];   // [256][64][1024]
  const float* weight = (const float*)d_in[1];   // [2][2][4096][1024]
  const float* bias   = (const float*)d_in[2];   // [2][2][4096]
  const float* fc_w   = (const float*)d_in[3];   // [10][1024]
  const float* fc_b   = (const float*)d_in[4];   // [10]
  float* out = (float*)d_out;                    // [64][10]

  auto align = [](size_t v) { return (v + 255) & ~(size_t)255; };
  const size_t flags_sz = (size_t)NBLK * FLAG_STRIDE * sizeof(unsigned);   // 32 KB
  const size_t x16_sz   = (size_t)S_LEN * BATCH * HID * sizeof(h16);       // 32 MB
  const size_t h0r_sz   = (size_t)RING_D * BATCH * HID * sizeof(h16);      // 512 KB
  const size_t h1r_sz   = (size_t)2 * BATCH * HID * sizeof(h16);           // 256 KB

  char* p = (char*)d_ws;
  unsigned* flags = (unsigned*)p; p += align(flags_sz);
  h16* x16 = (h16*)p; p += align(x16_sz);
  h16* h0r = (h16*)p; p += align(h0r_sz);
  h16* h1r = (h16*)p; p += align(h1r_sz);

  hipMemsetAsync(flags, 0, flags_sz, stream);
  hipMemsetAsync(h0r, 0, h0r_sz, stream);
  hipMemsetAsync(h1r, 0, h1r_sz, stream);

  xconv_kernel<<<dim3(2048), 256, 0, stream>>>(x, x16);

  lstm_persistent<<<dim3(NBLK), dim3(512), 0, stream>>>(
      x16, weight, bias, h0r, h1r, flags);

  // final h of top layer: t = 255 -> h1 ring slot 1
  fc_kernel<<<dim3((BATCH * 10 * 64) / 256), 256, 0, stream>>>(
      h1r + (size_t)BATCH * HID, fc_w, fc_b, out);
}

// Round 14
// 2637.159 us; speedup vs baseline: 1.1270x; 1.0245x over previous
//
#include <hip/hip_runtime.h>
#include <cstdint>
#include <cstddef>

#define S_LEN 256
#define BATCH 64
#define HID   1024
#define GATES 4096
#define NBLK  256
#define RING_D 4         // h0 ring depth
#define FLAG_STRIDE 32   // 32 uints = 128 B: one cache line per flag

typedef _Float16 h16;
typedef _Float16 h16x8 __attribute__((ext_vector_type(8)));
typedef _Float16 h16x4 __attribute__((ext_vector_type(4)));
typedef float    f32x4 __attribute__((ext_vector_type(4)));

// ---------------------------------------------------------------------------
// x fp32 -> fp16 (one pass)
// ---------------------------------------------------------------------------
__global__ __launch_bounds__(256)
void xconv_kernel(const float* __restrict__ x, h16* __restrict__ x16)
{
  const int n4 = S_LEN * BATCH * HID / 4;
  const int stride = gridDim.x * 256;
  for (int i = blockIdx.x * 256 + threadIdx.x; i < n4; i += stride) {
    f32x4 v = ((const f32x4*)x)[i];
    h16x4 o;
    o[0] = (h16)v[0]; o[1] = (h16)v[1]; o[2] = (h16)v[2]; o[3] = (h16)v[3];
    ((h16x4*)x16)[i] = o;
  }
}

// ---------------------------------------------------------------------------
// Device-scope (sc1) 16B load: bypasses L1+L2, reads L3 coherence point.
// Issued without internal wait so batches pipeline; caller fences with
// vmcnt(0) + sched_barrier(0) before use (rule-18).
// ---------------------------------------------------------------------------
#define RLOAD(dst, ptr, OFFSTR)                                         \
  asm volatile("global_load_dwordx4 %0, %1, off offset:" OFFSTR " sc1"  \
               : "=&v"(dst) : "v"(ptr) : "memory")

// ---------------------------------------------------------------------------
// In-wave flag poll: each lane watches 2 of the 128 flags (lane, lane+64);
// the wave proceeds only when all its lanes pass -> block-wide consensus
// without any __syncthreads. s_sleep(1) caps poll request pressure.
// ---------------------------------------------------------------------------
__device__ __forceinline__ void wave_poll(const unsigned* flags, int base,
                                          unsigned tgt, int lane)
{
  const unsigned* f0 = &flags[(size_t)(base + lane) * FLAG_STRIDE];
  const unsigned* f1 = &flags[(size_t)(base + 64 + lane) * FLAG_STRIDE];
  while (__hip_atomic_load(f0, __ATOMIC_RELAXED, __HIP_MEMORY_SCOPE_AGENT) < tgt ||
         __hip_atomic_load(f1, __ATOMIC_RELAXED, __HIP_MEMORY_SCOPE_AGENT) < tgt)
    __builtin_amdgcn_s_sleep(1);
}

// ---------------------------------------------------------------------------
// Persistent 2-layer decoupled-pipeline LSTM, shadowed input GEMM (R13) +
// in-wave flag polling (no wait-side syncthreads) + 2-round reduce.
// 256 WGs x 512 thr. Group 0 = blocks 0..127 (layer 0), group 1 = layer 1.
// Per iteration t:
//   SHADOW : accI = input-half partials (x16[t] / h0[t]); L1 waves first
//            in-wave-poll L0 flags >= t+1.
//   WAIT   : in-wave poll own flags >= t; L0 also polls L1 >= t+1-RING_D.
//   CRITICAL: load h_own[t-1] (16x16B sc1/wave-lane), 32 MFMAs on accI,
//            2-round 8-way LDS reduce (4 syncthreads total), activations,
//            sc1 h stores, publish flag t+1.
// LDS: 128KB weights + 32KB plds = exactly 160 KiB (CU max).
// No cache maintenance anywhere: mutable data all-sc1, immutable plain.
// ---------------------------------------------------------------------------
__global__ __launch_bounds__(512, 1)
void lstm_persistent(const h16* __restrict__ x16,
                     const float* __restrict__ weight,
                     const float* __restrict__ bias,
                     h16* __restrict__ h0r,
                     h16* __restrict__ h1r,
                     unsigned* __restrict__ flags)
{
  __shared__ h16   wlds[65536];          // 128 KB
  __shared__ float plds[2][8][16][32];   // 32 KB

  const int wg    = blockIdx.x;
  const int layer = wg >> 7;
  const int j0    = (wg & 127) * 8;
  const int tid   = threadIdx.x;
  const int wave  = tid >> 6, lane = tid & 63;
  const int l15   = lane & 15, l16 = lane >> 4;
  const int BH    = BATCH * HID;

  // ---- one-time: pack weights fp32->fp16 into LDS ----
  // c = (((part*8 + w)*2 + n2)*4 + s)*64 + ln
  {
    const float* wsrc = weight + (size_t)layer * 2 * GATES * HID;
    for (int c = tid; c < 8192; c += 512) {
      const int ln = c & 63, s = (c >> 6) & 3, n2 = (c >> 8) & 1,
                w = (c >> 9) & 7, part = c >> 12;
      const int lc  = n2 * 16 + (ln & 15);              // local col 0..31
      const int col = (lc >> 3) * HID + j0 + (lc & 7);  // global gate col
      const int k   = w * 128 + s * 32 + (ln >> 4) * 8; // K within part
      const float* p = wsrc + (part ? (size_t)GATES * HID : (size_t)0)
                            + (size_t)col * HID + k;
      h16x8 v;
#pragma unroll
      for (int e = 0; e < 8; ++e) v[e] = (h16)p[e];
      *(h16x8*)&wlds[(size_t)c * 8] = v;
    }
  }
  // combined bias (threads 0-255 use it)
  float bc[4];
  {
    const int j = tid & 7;
#pragma unroll
    for (int gg = 0; gg < 4; ++gg) {
      const int col = gg * HID + j0 + j;
      bc[gg] = bias[(size_t)layer * 2 * GATES + col] +
               bias[(size_t)layer * 2 * GATES + GATES + col];
    }
  }
  float creg2[2] = {0.f, 0.f};   // thread tid<256: c for i = 2p + (tid>>7)
  __syncthreads();

  const int own_base = layer * 128;
  const int oth_base = (1 - layer) * 128;
  const h16* bbI = wlds + (size_t)wave * 4096 + lane * 8;  // input-part B
  const h16* bbH = bbI + 32768;                            // hidden-part B
  const int kw = wave * 128 + l16 * 8;                     // per-wave K base

  for (int t = 0; t < S_LEN; ++t) {
    // ================= SHADOW: input-half partials for step t ==============
    const h16* As;
    if (layer == 0) {
      As = x16 + (size_t)t * BH;                       // always ready
    } else {
      wave_poll(flags, oth_base, (unsigned)(t + 1), lane);   // h0[t] ready
      As = h0r + (size_t)(t % RING_D) * BH;
    }

    f32x4 accI[4][2];
#pragma unroll
    for (int i = 0; i < 4; ++i)
#pragma unroll
      for (int n2 = 0; n2 < 2; ++n2) accI[i][n2] = (f32x4)0.f;

#pragma unroll
    for (int sc = 0; sc < 2; ++sc) {
      h16x8 aS[2][4];
      if (layer == 0) {
#pragma unroll
        for (int ss = 0; ss < 2; ++ss)
#pragma unroll
          for (int i = 0; i < 4; ++i)
            aS[ss][i] = *(const h16x8*)(As + (size_t)(i * 16 + l15) * HID +
                                        kw + (sc * 2 + ss) * 32);
      } else {
#pragma unroll
        for (int i = 0; i < 4; ++i) {
          const h16* ap = As + (size_t)(i * 16 + l15) * HID + kw + sc * 64;
          RLOAD(aS[0][i], ap, "0");
          RLOAD(aS[1][i], ap, "64");
        }
        asm volatile("s_waitcnt vmcnt(0)" ::: "memory");
        __builtin_amdgcn_sched_barrier(0);
      }
#pragma unroll
      for (int ss = 0; ss < 2; ++ss) {
        const int s = sc * 2 + ss;
        const h16x8 b0 = *(const h16x8*)(bbI + s * 512);
        const h16x8 b1 = *(const h16x8*)(bbI + 2048 + s * 512);
#pragma unroll
        for (int i = 0; i < 4; ++i) {
          accI[i][0] = __builtin_amdgcn_mfma_f32_16x16x32_f16(aS[ss][i], b0, accI[i][0], 0, 0, 0);
          accI[i][1] = __builtin_amdgcn_mfma_f32_16x16x32_f16(aS[ss][i], b1, accI[i][1], 0, 0, 0);
        }
      }
    }

    // ================= WAIT (in-wave): own @ t; L0 ring safety ============
    if (t) wave_poll(flags, own_base, (unsigned)t, lane);
    if (layer == 0) {
      const int ct = t + 1 - RING_D;
      if (ct > 0) wave_poll(flags, oth_base, (unsigned)ct, lane);
    }

    // ================= CRITICAL: hidden-half + reduce + publish ===========
    const h16* Ah;                    // h_own[t-1]
    h16* Hout;                        // h_own[t]
    if (layer == 0) {
      Ah   = h0r + (size_t)((t + RING_D - 1) % RING_D) * BH;
      Hout = h0r + (size_t)(t % RING_D) * BH;
    } else {
      Ah   = h1r + (size_t)((t + 1) & 1) * BH;
      Hout = h1r + (size_t)(t & 1) * BH;
    }

    h16x8 aH[4][4];
#pragma unroll
    for (int i = 0; i < 4; ++i) {
      const h16* ap = Ah + (size_t)(i * 16 + l15) * HID + kw;
      RLOAD(aH[i][0], ap, "0");
      RLOAD(aH[i][1], ap, "64");
      RLOAD(aH[i][2], ap, "128");
      RLOAD(aH[i][3], ap, "192");
    }
    asm volatile("s_waitcnt vmcnt(0)" ::: "memory");
    __builtin_amdgcn_sched_barrier(0);

    f32x4 acc[4][2];
#pragma unroll
    for (int i = 0; i < 4; ++i)
#pragma unroll
      for (int n2 = 0; n2 < 2; ++n2) acc[i][n2] = accI[i][n2];

#pragma unroll
    for (int s = 0; s < 4; ++s) {
      const h16x8 b0 = *(const h16x8*)(bbH + s * 512);
      const h16x8 b1 = *(const h16x8*)(bbH + 2048 + s * 512);
#pragma unroll
      for (int i = 0; i < 4; ++i) {
        acc[i][0] = __builtin_amdgcn_mfma_f32_16x16x32_f16(aH[i][s], b0, acc[i][0], 0, 0, 0);
        acc[i][1] = __builtin_amdgcn_mfma_f32_16x16x32_f16(aH[i][s], b1, acc[i][1], 0, 0, 0);
      }
    }

    // ---- 8-way cross-wave reduce, 2 rounds of 2 m-tiles (4 syncthreads) ---
#pragma unroll
    for (int p = 0; p < 2; ++p) {
#pragma unroll
      for (int ii = 0; ii < 2; ++ii) {
        const int i = p * 2 + ii;
#pragma unroll
        for (int n2 = 0; n2 < 2; ++n2)
#pragma unroll
          for (int q = 0; q < 4; ++q) {
            const int r = l16 * 4 + q;                        // 0..15
            const int colS = (n2 * 16 + l15) ^ ((r & 7) << 2);
            plds[ii][wave][r][colS] = acc[i][n2][q];
          }
      }
      __syncthreads();
      if (tid < 256) {
        const int ii = tid >> 7, r = (tid >> 3) & 15, j = tid & 7;
        float gv[4];
#pragma unroll
        for (int gg = 0; gg < 4; ++gg) {
          const int colS = (gg * 8 + j) ^ ((r & 7) << 2);
          float s = bc[gg];
#pragma unroll
        for (int w = 0; w < 8; ++w) s += plds[ii][w][r][colS];
          gv[gg] = s;
        }
        const float ig = 1.f / (1.f + __expf(-gv[0]));
        const float fg = 1.f / (1.f + __expf(-gv[1]));
        const float gt = 1.f - 2.f / (__expf(2.f * gv[2]) + 1.f);
        const float og = 1.f / (1.f + __expf(-gv[3]));
        const float cn = fg * creg2[p] + ig * gt;
        creg2[p] = cn;
        const float th = 1.f - 2.f / (__expf(2.f * cn) + 1.f);
        union { h16 f; unsigned short u; } hb;
        hb.f = (h16)(og * th);
        const int row = (p * 2 + ii) * 16 + r;
        __hip_atomic_store(
            (unsigned short*)&Hout[(size_t)row * HID + j0 + j],
            hb.u, __ATOMIC_RELAXED, __HIP_MEMORY_SCOPE_AGENT);
      }
      __syncthreads();   // drains each wave's vmcnt: h-stores at L3
    }

    // ---- publish step completion ----
    if (tid == 0)
      __hip_atomic_store(&flags[wg * FLAG_STRIDE], (unsigned)(t + 1),
                         __ATOMIC_RELAXED, __HIP_MEMORY_SCOPE_AGENT);
  }
}

// ---------------------------------------------------------------------------
// out[m][cls] = h[m] . fc_w[cls] + fc_b[cls]. One wave per output.
// ---------------------------------------------------------------------------
__global__ __launch_bounds__(256)
void fc_kernel(const h16* __restrict__ h,
               const float* __restrict__ fw,
               const float* __restrict__ fb,
               float* __restrict__ out)
{
  const int gw = (blockIdx.x * blockDim.x + threadIdx.x) >> 6;
  const int lane = threadIdx.x & 63;
  if (gw >= BATCH * 10) return;
  const int m = gw / 10, cls = gw % 10;
  float s = 0.f;
  for (int k = lane; k < HID; k += 64)
    s += (float)h[(size_t)m * HID + k] * fw[(size_t)cls * HID + k];
#pragma unroll
  for (int off = 32; off; off >>= 1) s += __shfl_down(s, off);
  if (lane == 0) out[m * 10 + cls] = s + fb[cls];
}

// ---------------------------------------------------------------------------
extern "C" void kernel_launch(void* const* d_in, const int* in_sizes, int n_in,
                              void* d_out, int out_size, void* d_ws, size_t ws_size,
                              hipStream_t stream)
{
  const float* x      = (const float*)d_in[0];   // [256][64][1024]
  const float* weight = (const float*)d_in[1];   // [2][2][4096][1024]
  const float* bias   = (const float*)d_in[2];   // [2][2][4096]
  const float* fc_w   = (const float*)d_in[3];   // [10][1024]
  const float* fc_b   = (const float*)d_in[4];   // [10]
  float* out = (float*)d_out;                    // [64][10]

  auto align = [](size_t v) { return (v + 255) & ~(size_t)255; };
  const size_t flags_sz = (size_t)NBLK * FLAG_STRIDE * sizeof(unsigned);   // 32 KB
  const size_t x16_sz   = (size_t)S_LEN * BATCH * HID * sizeof(h16);       // 32 MB
  const size_t h0r_sz   = (size_t)RING_D * BATCH * HID * sizeof(h16);      // 512 KB
  const size_t h1r_sz   = (size_t)2 * BATCH * HID * sizeof(h16);           // 256 KB

  char* p = (char*)d_ws;
  unsigned* flags = (unsigned*)p; p += align(flags_sz);
  h16* x16 = (h16*)p; p += align(x16_sz);
  h16* h0r = (h16*)p; p += align(h0r_sz);
  h16* h1r = (h16*)p; p += align(h1r_sz);

  hipMemsetAsync(flags, 0, flags_sz, stream);
  hipMemsetAsync(h0r, 0, h0r_sz, stream);
  hipMemsetAsync(h1r, 0, h1r_sz, stream);

  xconv_kernel<<<dim3(2048), 256, 0, stream>>>(x, x16);

  lstm_persistent<<<dim3(NBLK), dim3(512), 0, stream>>>(
      x16, weight, bias, h0r, h1r, flags);

  // final h of top layer: t = 255 -> h1 ring slot 1
  fc_kernel<<<dim3((BATCH * 10 * 64) / 256), 256, 0, stream>>>(
      h1r + (size_t)BATCH * HID, fc_w, fc_b, out);
}